// Round 4
// baseline (126.189 us; speedup 1.0000x reference)
//
#include <hip/hip_runtime.h>

// rfft512 over 32768 rows, one wave64 per row.
// z[n] = x[2n] + i*x[2n+1] -> FFT_256 (Stockham radix-4 DIF, 4 stages) ->
// rfft untangle -> bins 0..256 (Re plane then Im plane).
//
// Stage A is fused with the global load: lane t's stage-A read set
// {z[t], z[t+64], z[t+128], z[t+192]} is loaded straight from global as four
// coalesced dwordx2 nontemporal loads, so stage A runs in registers (no
// initial LDS round-trip). Stages B..D go through XOR-swizzled float2 LDS
// ping-pong. Wave-synchronous: one wave owns a row; stage boundaries need
// only s_waitcnt lgkmcnt(0) (wave64 lockstep), no __syncthreads.

#define NFFT 512
#define WPB  4   // waves (=rows) per 256-thread block

typedef float vf2 __attribute__((ext_vector_type(2)));  // native vector for nontemporal builtins

__device__ __forceinline__ int SW(int i) { return i ^ ((i >> 2) & 12); }

__device__ __forceinline__ void waveSyncLds() {
    asm volatile("s_waitcnt lgkmcnt(0)" ::: "memory");
}

__global__ __launch_bounds__(256) void rfft512_kernel(
    const float* __restrict__ x, float* __restrict__ out, int batch)
{
    __shared__ __align__(16) float2 lds[WPB][2][256];
    const int t = threadIdx.x & 63;
    const int w = threadIdx.x >> 6;
    long long b = (long long)blockIdx.x * WPB + w;
    if (b >= batch) b = batch - 1;   // safe clamp (grid divides exactly anyway)

    float2* buf0 = lds[w][0];
    float2* buf1 = lds[w][1];
    const float NEG2PI = -6.28318530717958647692f;
    const float C45 = 0.70710678118654752440f;

    // ---- Stage A (n=256, s=1, p=t), fused with global load, in-register.
    {
        const vf2* xf2 = (const vf2*)(x + b * NFFT);
        vf2 a  = __builtin_nontemporal_load(&xf2[t]);
        vf2 bb = __builtin_nontemporal_load(&xf2[t + 64]);
        vf2 c  = __builtin_nontemporal_load(&xf2[t + 128]);
        vf2 d  = __builtin_nontemporal_load(&xf2[t + 192]);
        float apcr = a.x + c.x, apci = a.y + c.y;
        float amcr = a.x - c.x, amci = a.y - c.y;
        float bpdr = bb.x + d.x, bpdi = bb.y + d.y;
        float bmdr = bb.x - d.x, bmdi = bb.y - d.y;
        float y0r = apcr + bpdr, y0i = apci + bpdi;
        float u1r = amcr + bmdi, u1i = amci - bmdr;
        float u2r = apcr - bpdr, u2i = apci - bpdi;
        float u3r = amcr - bmdi, u3i = amci + bmdr;
        float sn, cs;
        __sincosf(NEG2PI * (float)t * (1.0f / 256.0f), &sn, &cs);
        float w1r = cs, w1i = sn;
        float w2r = cs * cs - sn * sn, w2i = 2.0f * cs * sn;
        float w3r = w1r * w2r - w1i * w2i, w3i = w1r * w2i + w1i * w2r;
        int wb = (4 * t) ^ (t & 12);           // SW(4t), multiple of 4
        float4* d4 = (float4*)buf1;
        d4[wb >> 1]       = make_float4(y0r, y0i,
                                        w1r * u1r - w1i * u1i, w1r * u1i + w1i * u1r);
        d4[(wb >> 1) + 1] = make_float4(w2r * u2r - w2i * u2i, w2r * u2i + w2i * u2r,
                                        w3r * u3r - w3i * u3i, w3r * u3i + w3i * u3r);
    }
    waveSyncLds();

    // ---- Stage B: n=64, s=4 : p=t>>2, wbase=(t&3)+16*(t>>2), ws=4
    {
        int rb = SW(t);
        float2 a = buf1[rb], bb = buf1[rb + 64], c = buf1[rb + 128], d = buf1[rb + 192];
        float apcr = a.x + c.x, apci = a.y + c.y;
        float amcr = a.x - c.x, amci = a.y - c.y;
        float bpdr = bb.x + d.x, bpdi = bb.y + d.y;
        float bmdr = bb.x - d.x, bmdi = bb.y - d.y;
        float y0r = apcr + bpdr, y0i = apci + bpdi;
        float u1r = amcr + bmdi, u1i = amci - bmdr;
        float u2r = apcr - bpdr, u2i = apci - bpdi;
        float u3r = amcr - bmdi, u3i = amci + bmdr;
        float sn, cs;
        __sincosf(NEG2PI * (float)(t >> 2) * (1.0f / 64.0f), &sn, &cs);
        float w1r = cs, w1i = sn;
        float w2r = cs * cs - sn * sn, w2i = 2.0f * cs * sn;
        float w3r = w1r * w2r - w1i * w2i, w3i = w1r * w2i + w1i * w2r;
        int wbase = (t & 3) + 16 * (t >> 2);
        buf0[SW(wbase)]      = make_float2(y0r, y0i);
        buf0[SW(wbase + 4)]  = make_float2(w1r * u1r - w1i * u1i, w1r * u1i + w1i * u1r);
        buf0[SW(wbase + 8)]  = make_float2(w2r * u2r - w2i * u2i, w2r * u2i + w2i * u2r);
        buf0[SW(wbase + 12)] = make_float2(w3r * u3r - w3i * u3i, w3r * u3i + w3i * u3r);
    }
    waveSyncLds();

    // ---- Stage C: n=16, s=16 : p=t>>4, wbase=(t&15)+64*(t>>4), ws=16
    {
        int rb = SW(t);
        float2 a = buf0[rb], bb = buf0[rb + 64], c = buf0[rb + 128], d = buf0[rb + 192];
        float apcr = a.x + c.x, apci = a.y + c.y;
        float amcr = a.x - c.x, amci = a.y - c.y;
        float bpdr = bb.x + d.x, bpdi = bb.y + d.y;
        float bmdr = bb.x - d.x, bmdi = bb.y - d.y;
        float y0r = apcr + bpdr, y0i = apci + bpdi;
        float u1r = amcr + bmdi, u1i = amci - bmdr;
        float u2r = apcr - bpdr, u2i = apci - bpdi;
        float u3r = amcr - bmdi, u3i = amci + bmdr;
        float sn, cs;
        __sincosf(NEG2PI * (float)(t >> 4) * (1.0f / 16.0f), &sn, &cs);
        float w1r = cs, w1i = sn;
        float w2r = cs * cs - sn * sn, w2i = 2.0f * cs * sn;
        float w3r = w1r * w2r - w1i * w2i, w3i = w1r * w2i + w1i * w2r;
        int wbase = (t & 15) + 64 * (t >> 4);
        buf1[SW(wbase)]      = make_float2(y0r, y0i);
        buf1[SW(wbase + 16)] = make_float2(w1r * u1r - w1i * u1i, w1r * u1i + w1i * u1r);
        buf1[SW(wbase + 32)] = make_float2(w2r * u2r - w2i * u2i, w2r * u2i + w2i * u2r);
        buf1[SW(wbase + 48)] = make_float2(w3r * u3r - w3i * u3i, w3r * u3i + w3i * u3r);
    }
    waveSyncLds();

    // ---- Stage D: n=4, s=64 : p=0 (unit twiddles), lane-local (wbase=t, ws=64).
    // Keep Z[t+64j] in registers; also write to LDS for the partner gather.
    float zr[4], zi[4];
    {
        int rb = SW(t);
        float2 a = buf1[rb], bb = buf1[rb + 64], c = buf1[rb + 128], d = buf1[rb + 192];
        float apcr = a.x + c.x, apci = a.y + c.y;
        float amcr = a.x - c.x, amci = a.y - c.y;
        float bpdr = bb.x + d.x, bpdi = bb.y + d.y;
        float bmdr = bb.x - d.x, bmdi = bb.y - d.y;
        zr[0] = apcr + bpdr; zi[0] = apci + bpdi;
        zr[1] = amcr + bmdi; zi[1] = amci - bmdr;
        zr[2] = apcr - bpdr; zi[2] = apci - bpdi;
        zr[3] = amcr - bmdi; zi[3] = amci + bmdr;
        buf0[rb]       = make_float2(zr[0], zi[0]);
        buf0[rb + 64]  = make_float2(zr[1], zi[1]);
        buf0[rb + 128] = make_float2(zr[2], zi[2]);
        buf0[rb + 192] = make_float2(zr[3], zi[3]);
    }
    waveSyncLds();

    // ---- rfft untangle: X[k] = A + exp(-2*pi*i*k/512)*B, k = t+64j.
    // One sincos: w(t+64j) = w(t) * exp(-i*pi*j/4) with constant rotations.
    float wr[4], wi[4];
    {
        float sn, cs;
        __sincosf(NEG2PI * (float)t * (1.0f / 512.0f), &sn, &cs);
        wr[0] = cs;              wi[0] = sn;
        wr[1] = C45 * (cs + sn); wi[1] = C45 * (sn - cs);
        wr[2] = sn;              wi[2] = -cs;
        wr[3] = C45 * (sn - cs); wi[3] = -C45 * (cs + sn);
    }
    float* outRe = out + b * 257;
    float* outIm = out + (long long)batch * 257 + b * 257;
#pragma unroll
    for (int j = 0; j < 4; ++j) {
        int k = t + 64 * j;
        int km = (256 - k) & 255;
        float2 pm = buf0[SW(km)];
        float S = zr[j] + pm.x;        // 2*Ar
        float T = zi[j] - pm.y;        // 2*Ai
        float U = zi[j] + pm.y;        // 2*Br
        float V = zr[j] - pm.x;        // -2*Bi
        __builtin_nontemporal_store(0.5f * (S + wr[j] * U + wi[j] * V), &outRe[k]);
        __builtin_nontemporal_store(0.5f * (T - wr[j] * V + wi[j] * U), &outIm[k]);
    }
    if (t == 0) {
        __builtin_nontemporal_store(zr[0] - zi[0], &outRe[256]);  // X[256]
        __builtin_nontemporal_store(0.0f, &outIm[256]);
    }
}

extern "C" void kernel_launch(void* const* d_in, const int* in_sizes, int n_in,
                              void* d_out, int out_size, void* d_ws, size_t ws_size,
                              hipStream_t stream)
{
    const float* x = (const float*)d_in[0];
    float* out = (float*)d_out;
    const int batch = in_sizes[0] / NFFT;        // 32768
    const int grid = (batch + WPB - 1) / WPB;    // 8192 blocks of 256
    rfft512_kernel<<<grid, 256, 0, stream>>>(x, out, batch);
}

// Round 5
// 110.579 us; speedup vs baseline: 1.1412x; 1.1412x over previous
//
#include <hip/hip_runtime.h>

// rfft512 over 32768 rows, one wave64 per row.
// z[n] = x[2n] + i*x[2n+1] -> FFT_256 (Stockham radix-4 DIF, 4 stages) ->
// rfft untangle -> bins 0..256 (Re plane then Im plane).
//
// Stage A is fused with the global load: lane t's stage-A read set
// {z[t], z[t+64], z[t+128], z[t+192]} is loaded straight from global as four
// coalesced dwordx2 loads (cached — the harness's input-restore leaves x hot
// in LLC; nontemporal hints measurably regress, R3: +17us). Stages B..D go
// through XOR-swizzled float2 LDS ping-pong. Wave-synchronous: one wave owns
// a row; stage boundaries need only s_waitcnt lgkmcnt(0), no __syncthreads.

#define NFFT 512
#define WPB  4   // waves (=rows) per 256-thread block

__device__ __forceinline__ int SW(int i) { return i ^ ((i >> 2) & 12); }

__device__ __forceinline__ void waveSyncLds() {
    asm volatile("s_waitcnt lgkmcnt(0)" ::: "memory");
}

__global__ __launch_bounds__(256) void rfft512_kernel(
    const float* __restrict__ x, float* __restrict__ out, int batch)
{
    __shared__ __align__(16) float2 lds[WPB][2][256];
    const int t = threadIdx.x & 63;
    const int w = threadIdx.x >> 6;
    long long b = (long long)blockIdx.x * WPB + w;
    if (b >= batch) b = batch - 1;   // safe clamp (grid divides exactly anyway)

    float2* buf0 = lds[w][0];
    float2* buf1 = lds[w][1];
    const float NEG2PI = -6.28318530717958647692f;
    const float C45 = 0.70710678118654752440f;

    // ---- Stage A (n=256, s=1, p=t), fused with global load, in-register.
    {
        const float2* xf2 = (const float2*)(x + b * NFFT);
        float2 a  = xf2[t];
        float2 bb = xf2[t + 64];
        float2 c  = xf2[t + 128];
        float2 d  = xf2[t + 192];
        float apcr = a.x + c.x, apci = a.y + c.y;
        float amcr = a.x - c.x, amci = a.y - c.y;
        float bpdr = bb.x + d.x, bpdi = bb.y + d.y;
        float bmdr = bb.x - d.x, bmdi = bb.y - d.y;
        float y0r = apcr + bpdr, y0i = apci + bpdi;
        float u1r = amcr + bmdi, u1i = amci - bmdr;
        float u2r = apcr - bpdr, u2i = apci - bpdi;
        float u3r = amcr - bmdi, u3i = amci + bmdr;
        float sn, cs;
        __sincosf(NEG2PI * (float)t * (1.0f / 256.0f), &sn, &cs);
        float w1r = cs, w1i = sn;
        float w2r = cs * cs - sn * sn, w2i = 2.0f * cs * sn;
        float w3r = w1r * w2r - w1i * w2i, w3i = w1r * w2i + w1i * w2r;
        int wb = (4 * t) ^ (t & 12);           // SW(4t), multiple of 4
        float4* d4 = (float4*)buf1;
        d4[wb >> 1]       = make_float4(y0r, y0i,
                                        w1r * u1r - w1i * u1i, w1r * u1i + w1i * u1r);
        d4[(wb >> 1) + 1] = make_float4(w2r * u2r - w2i * u2i, w2r * u2i + w2i * u2r,
                                        w3r * u3r - w3i * u3i, w3r * u3i + w3i * u3r);
    }
    waveSyncLds();

    // ---- Stage B: n=64, s=4 : p=t>>2, wbase=(t&3)+16*(t>>2), ws=4
    {
        int rb = SW(t);
        float2 a = buf1[rb], bb = buf1[rb + 64], c = buf1[rb + 128], d = buf1[rb + 192];
        float apcr = a.x + c.x, apci = a.y + c.y;
        float amcr = a.x - c.x, amci = a.y - c.y;
        float bpdr = bb.x + d.x, bpdi = bb.y + d.y;
        float bmdr = bb.x - d.x, bmdi = bb.y - d.y;
        float y0r = apcr + bpdr, y0i = apci + bpdi;
        float u1r = amcr + bmdi, u1i = amci - bmdr;
        float u2r = apcr - bpdr, u2i = apci - bpdi;
        float u3r = amcr - bmdi, u3i = amci + bmdr;
        float sn, cs;
        __sincosf(NEG2PI * (float)(t >> 2) * (1.0f / 64.0f), &sn, &cs);
        float w1r = cs, w1i = sn;
        float w2r = cs * cs - sn * sn, w2i = 2.0f * cs * sn;
        float w3r = w1r * w2r - w1i * w2i, w3i = w1r * w2i + w1i * w2r;
        int wbase = (t & 3) + 16 * (t >> 2);
        buf0[SW(wbase)]      = make_float2(y0r, y0i);
        buf0[SW(wbase + 4)]  = make_float2(w1r * u1r - w1i * u1i, w1r * u1i + w1i * u1r);
        buf0[SW(wbase + 8)]  = make_float2(w2r * u2r - w2i * u2i, w2r * u2i + w2i * u2r);
        buf0[SW(wbase + 12)] = make_float2(w3r * u3r - w3i * u3i, w3r * u3i + w3i * u3r);
    }
    waveSyncLds();

    // ---- Stage C: n=16, s=16 : p=t>>4, wbase=(t&15)+64*(t>>4), ws=16
    {
        int rb = SW(t);
        float2 a = buf0[rb], bb = buf0[rb + 64], c = buf0[rb + 128], d = buf0[rb + 192];
        float apcr = a.x + c.x, apci = a.y + c.y;
        float amcr = a.x - c.x, amci = a.y - c.y;
        float bpdr = bb.x + d.x, bpdi = bb.y + d.y;
        float bmdr = bb.x - d.x, bmdi = bb.y - d.y;
        float y0r = apcr + bpdr, y0i = apci + bpdi;
        float u1r = amcr + bmdi, u1i = amci - bmdr;
        float u2r = apcr - bpdr, u2i = apci - bpdi;
        float u3r = amcr - bmdi, u3i = amci + bmdr;
        float sn, cs;
        __sincosf(NEG2PI * (float)(t >> 4) * (1.0f / 16.0f), &sn, &cs);
        float w1r = cs, w1i = sn;
        float w2r = cs * cs - sn * sn, w2i = 2.0f * cs * sn;
        float w3r = w1r * w2r - w1i * w2i, w3i = w1r * w2i + w1i * w2r;
        int wbase = (t & 15) + 64 * (t >> 4);
        buf1[SW(wbase)]      = make_float2(y0r, y0i);
        buf1[SW(wbase + 16)] = make_float2(w1r * u1r - w1i * u1i, w1r * u1i + w1i * u1r);
        buf1[SW(wbase + 32)] = make_float2(w2r * u2r - w2i * u2i, w2r * u2i + w2i * u2r);
        buf1[SW(wbase + 48)] = make_float2(w3r * u3r - w3i * u3i, w3r * u3i + w3i * u3r);
    }
    waveSyncLds();

    // ---- Stage D: n=4, s=64 : p=0 (unit twiddles), lane-local (wbase=t, ws=64).
    // Keep Z[t+64j] in registers; also write to LDS for the partner gather.
    float zr[4], zi[4];
    {
        int rb = SW(t);
        float2 a = buf1[rb], bb = buf1[rb + 64], c = buf1[rb + 128], d = buf1[rb + 192];
        float apcr = a.x + c.x, apci = a.y + c.y;
        float amcr = a.x - c.x, amci = a.y - c.y;
        float bpdr = bb.x + d.x, bpdi = bb.y + d.y;
        float bmdr = bb.x - d.x, bmdi = bb.y - d.y;
        zr[0] = apcr + bpdr; zi[0] = apci + bpdi;
        zr[1] = amcr + bmdi; zi[1] = amci - bmdr;
        zr[2] = apcr - bpdr; zi[2] = apci - bpdi;
        zr[3] = amcr - bmdi; zi[3] = amci + bmdr;
        buf0[rb]       = make_float2(zr[0], zi[0]);
        buf0[rb + 64]  = make_float2(zr[1], zi[1]);
        buf0[rb + 128] = make_float2(zr[2], zi[2]);
        buf0[rb + 192] = make_float2(zr[3], zi[3]);
    }
    waveSyncLds();

    // ---- rfft untangle: X[k] = A + exp(-2*pi*i*k/512)*B, k = t+64j.
    // One sincos: w(t+64j) = w(t) * exp(-i*pi*j/4) with constant rotations.
    float wr[4], wi[4];
    {
        float sn, cs;
        __sincosf(NEG2PI * (float)t * (1.0f / 512.0f), &sn, &cs);
        wr[0] = cs;              wi[0] = sn;
        wr[1] = C45 * (cs + sn); wi[1] = C45 * (sn - cs);
        wr[2] = sn;              wi[2] = -cs;
        wr[3] = C45 * (sn - cs); wi[3] = -C45 * (cs + sn);
    }
    float* outRe = out + b * 257;
    float* outIm = out + (long long)batch * 257 + b * 257;
#pragma unroll
    for (int j = 0; j < 4; ++j) {
        int k = t + 64 * j;
        int km = (256 - k) & 255;
        float2 pm = buf0[SW(km)];
        float S = zr[j] + pm.x;        // 2*Ar
        float T = zi[j] - pm.y;        // 2*Ai
        float U = zi[j] + pm.y;        // 2*Br
        float V = zr[j] - pm.x;        // -2*Bi
        outRe[k] = 0.5f * (S + wr[j] * U + wi[j] * V);
        outIm[k] = 0.5f * (T - wr[j] * V + wi[j] * U);
    }
    if (t == 0) {
        outRe[256] = zr[0] - zi[0];    // X[256] = Re(Z[0]) - Im(Z[0])
        outIm[256] = 0.0f;
    }
}

extern "C" void kernel_launch(void* const* d_in, const int* in_sizes, int n_in,
                              void* d_out, int out_size, void* d_ws, size_t ws_size,
                              hipStream_t stream)
{
    const float* x = (const float*)d_in[0];
    float* out = (float*)d_out;
    const int batch = in_sizes[0] / NFFT;        // 32768
    const int grid = (batch + WPB - 1) / WPB;    // 8192 blocks of 256
    rfft512_kernel<<<grid, 256, 0, stream>>>(x, out, batch);
}